// Round 1
// baseline (3307.426 us; speedup 1.0000x reference)
//
#include <hip/hip_runtime.h>
#include <math.h>

#define SEQ 343
#define CCH 192
#define NWIN 128
#define NHEAD 6
#define TOK (NWIN * SEQ)  // 43904

__device__ __forceinline__ float gelu_tanh(float x) {
    const float k0 = 0.7978845608028654f;  // sqrt(2/pi)
    const float k1 = 0.044715f;
    float t = tanhf(k0 * (x + k1 * x * x * x));
    return 0.5f * x * (1.0f + t);
}

// ---------------- shift (+3 src) + window partition: x(28,56,28,192) -> xw(128,343,192)
__global__ __launch_bounds__(256) void k_shift_part(const float* __restrict__ x,
                                                    float* __restrict__ xw) {
    int idx = blockIdx.x * 256 + threadIdx.x;  // float4 index
    if (idx >= TOK * 48) return;
    int c4 = idx % 48;
    int tok = idx / 48;
    int t = tok % SEQ;
    int wn = tok / SEQ;
    int tw = t % 7, th = (t / 7) % 7, td = t / 49;
    int ww = wn & 3, wh = (wn >> 2) & 7, wd = wn >> 5;
    int sd = (wd * 7 + td + 3) % 28;
    int sh = (wh * 7 + th + 3) % 56;
    int sw = (ww * 7 + tw + 3) % 28;
    const float4* src = (const float4*)(x + (size_t)((sd * 56 + sh) * 28 + sw) * CCH);
    ((float4*)xw)[idx] = src[c4];
}

// ---------------- LayerNorm: one wave per row of 192
__global__ __launch_bounds__(256) void k_ln(const float* __restrict__ in,
                                            const float* __restrict__ w,
                                            const float* __restrict__ b,
                                            float* __restrict__ out, int rows) {
    int row = blockIdx.x * 4 + (threadIdx.x >> 6);
    int lane = threadIdx.x & 63;
    if (row >= rows) return;
    const float* p = in + (size_t)row * CCH;
    float v0 = p[lane], v1 = p[lane + 64], v2 = p[lane + 128];
    float s = v0 + v1 + v2;
#pragma unroll
    for (int off = 32; off > 0; off >>= 1) s += __shfl_xor(s, off);
    float mu = s * (1.0f / 192.0f);
    float d0 = v0 - mu, d1 = v1 - mu, d2 = v2 - mu;
    float vv = d0 * d0 + d1 * d1 + d2 * d2;
#pragma unroll
    for (int off = 32; off > 0; off >>= 1) vv += __shfl_xor(vv, off);
    float rs = rsqrtf(vv * (1.0f / 192.0f) + 1e-5f);
    float* q = out + (size_t)row * CCH;
    q[lane] = d0 * rs * w[lane] + b[lane];
    q[lane + 64] = d1 * rs * w[lane + 64] + b[lane + 64];
    q[lane + 128] = d2 * rs * w[lane + 128] + b[lane + 128];
}

// ---------------- final LN + window reverse + roll(+3) -> d_out
__global__ __launch_bounds__(256) void k_ln_out(const float* __restrict__ xw,
                                                const float* __restrict__ w,
                                                const float* __restrict__ b,
                                                float* __restrict__ out) {
    int row = blockIdx.x * 4 + (threadIdx.x >> 6);  // output token (d,h,w)
    int lane = threadIdx.x & 63;
    if (row >= TOK) return;
    int d = row / 1568;
    int hh = (row / 28) % 56;
    int wv = row % 28;
    int sd = (d + 25) % 28, sh = (hh + 53) % 56, sw = (wv + 25) % 28;
    int wn = (sd / 7) * 32 + (sh / 7) * 4 + (sw / 7);
    int t = (sd % 7) * 49 + (sh % 7) * 7 + (sw % 7);
    const float* p = xw + ((size_t)wn * SEQ + t) * CCH;
    float v0 = p[lane], v1 = p[lane + 64], v2 = p[lane + 128];
    float s = v0 + v1 + v2;
#pragma unroll
    for (int off = 32; off > 0; off >>= 1) s += __shfl_xor(s, off);
    float mu = s * (1.0f / 192.0f);
    float d0 = v0 - mu, d1 = v1 - mu, d2 = v2 - mu;
    float vv = d0 * d0 + d1 * d1 + d2 * d2;
#pragma unroll
    for (int off = 32; off > 0; off >>= 1) vv += __shfl_xor(vv, off);
    float rs = rsqrtf(vv * (1.0f / 192.0f) + 1e-5f);
    float* q = out + (size_t)row * CCH;
    q[lane] = d0 * rs * w[lane] + b[lane];
    q[lane + 64] = d1 * rs * w[lane + 64] + b[lane + 64];
    q[lane + 128] = d2 * rs * w[lane + 128] + b[lane + 128];
}

// ---------------- relative-position bias, transposed: biasT[h][k][q] = rpb[rel(q,k)][h]
__global__ void k_biaspre(const float* __restrict__ rpb, float* __restrict__ biasT) {
    int q = threadIdx.x;   // 0..342
    int k = blockIdx.x;    // 0..342
    int h = blockIdx.y;    // 0..5
    if (q >= SEQ) return;
    int qd = q / 49, qh = (q / 7) % 7, qw = q % 7;
    int kd = k / 49, kh = (k / 7) % 7, kw = k % 7;
    int rel = (qd - kd + 6) * 169 + (qh - kh + 6) * 13 + (qw - kw + 6);
    biasT[((size_t)h * SEQ + k) * SEQ + q] = rpb[(size_t)rel * NHEAD + h];
}

// ---------------- fp32 GEMM, 128x64 tile, 8x4 per thread.
// MODE 0: out = A@W + bias
// MODE 1: out += A@W + bias            (out doubles as residual base)
// MODE 2: GLU: W is [K,2N]; out = (A@W[:, :N]+bias[:N]) * gelu(A@W[:, N:]+bias[N:])
template <int MODE>
__global__ __launch_bounds__(256) void k_gemm(const float* __restrict__ A,
                                              const float* __restrict__ W,
                                              const float* __restrict__ bias,
                                              float* __restrict__ out,
                                              int M, int N, int K, int ldw) {
    __shared__ float As[16][128];
    __shared__ float Bs[16][64];
    __shared__ float Bs2[16][64];
    const int tid = threadIdx.x;
    const int n0 = blockIdx.x * 64;
    const size_t m0 = (size_t)blockIdx.y * 128;
    const int tx = tid & 15, ty = tid >> 4;
    float acc[8][4];
    float acc2[8][4];
#pragma unroll
    for (int i = 0; i < 8; ++i)
#pragma unroll
        for (int j = 0; j < 4; ++j) { acc[i][j] = 0.0f; acc2[i][j] = 0.0f; }
    const float* Ab = A + m0 * K;
    for (int kb = 0; kb < K; kb += 16) {
#pragma unroll
        for (int p = 0; p < 2; ++p) {
            int idx = tid + p * 256;       // 0..511 float4 slots of 128x16 tile
            int r = idx >> 2;              // 0..127
            int cg = (idx & 3) << 2;       // 0,4,8,12
            float4 v = *(const float4*)&Ab[(size_t)r * K + kb + cg];
            As[cg + 0][r] = v.x; As[cg + 1][r] = v.y;
            As[cg + 2][r] = v.z; As[cg + 3][r] = v.w;
        }
        {
            int wr = tid >> 4;             // 0..15
            int wc = (tid & 15) << 2;      // 0..60
            *(float4*)&Bs[wr][wc] = *(const float4*)&W[(size_t)(kb + wr) * ldw + n0 + wc];
            if (MODE == 2)
                *(float4*)&Bs2[wr][wc] =
                    *(const float4*)&W[(size_t)(kb + wr) * ldw + N + n0 + wc];
        }
        __syncthreads();
#pragma unroll
        for (int k = 0; k < 16; ++k) {
            float4 a0 = *(float4*)&As[k][ty * 8];
            float4 a1 = *(float4*)&As[k][ty * 8 + 4];
            float4 b0 = *(float4*)&Bs[k][tx * 4];
            float av[8] = {a0.x, a0.y, a0.z, a0.w, a1.x, a1.y, a1.z, a1.w};
            float bv[4] = {b0.x, b0.y, b0.z, b0.w};
#pragma unroll
            for (int i = 0; i < 8; ++i)
#pragma unroll
                for (int j = 0; j < 4; ++j) acc[i][j] += av[i] * bv[j];
            if (MODE == 2) {
                float4 b2 = *(float4*)&Bs2[k][tx * 4];
                float bw[4] = {b2.x, b2.y, b2.z, b2.w};
#pragma unroll
                for (int i = 0; i < 8; ++i)
#pragma unroll
                    for (int j = 0; j < 4; ++j) acc2[i][j] += av[i] * bw[j];
            }
        }
        __syncthreads();
    }
    float4 bb = *(const float4*)&bias[n0 + tx * 4];
    float4 bg = bb;
    if (MODE == 2) bg = *(const float4*)&bias[N + n0 + tx * 4];
#pragma unroll
    for (int i = 0; i < 8; ++i) {
        size_t r = m0 + ty * 8 + i;
        float* orow = out + r * (size_t)N + n0 + tx * 4;
        if (MODE == 0) {
            float4 v = {acc[i][0] + bb.x, acc[i][1] + bb.y,
                        acc[i][2] + bb.z, acc[i][3] + bb.w};
            *(float4*)orow = v;
        } else if (MODE == 1) {
            float4 c = *(float4*)orow;
            float4 v = {c.x + acc[i][0] + bb.x, c.y + acc[i][1] + bb.y,
                        c.z + acc[i][2] + bb.z, c.w + acc[i][3] + bb.w};
            *(float4*)orow = v;
        } else {
            float u0 = acc[i][0] + bb.x, g0 = acc2[i][0] + bg.x;
            float u1 = acc[i][1] + bb.y, g1 = acc2[i][1] + bg.y;
            float u2 = acc[i][2] + bb.z, g2 = acc2[i][2] + bg.z;
            float u3 = acc[i][3] + bb.w, g3 = acc2[i][3] + bg.w;
            float4 v = {u0 * gelu_tanh(g0), u1 * gelu_tanh(g1),
                        u2 * gelu_tanh(g2), u3 * gelu_tanh(g3)};
            *(float4*)orow = v;
        }
    }
}

// ---------------- attention: one block per (head, window); one lane per q-row.
// K/V staged in LDS (broadcast reads). mask read transposed via symmetry; bias pre-transposed.
__global__ __launch_bounds__(384) void k_attn(const float* __restrict__ qkv,
                                              const float* __restrict__ mask,
                                              const float* __restrict__ biasT,
                                              float* __restrict__ o) {
    __shared__ float Ks[SEQ][32];
    __shared__ float Vs[SEQ][32];
    const int h = blockIdx.x;   // 0..5
    const int wn = blockIdx.y;  // 0..127
    const int tid = threadIdx.x;
    const float* qw = qkv + (size_t)wn * SEQ * 576;
    for (int j = tid; j < SEQ * 8; j += 384) {
        int s = j >> 3, f = (j & 7) << 2;
        *(float4*)&Ks[s][f] = *(const float4*)&qw[(size_t)s * 576 + 192 + h * 32 + f];
        *(float4*)&Vs[s][f] = *(const float4*)&qw[(size_t)s * 576 + 384 + h * 32 + f];
    }
    __syncthreads();
    if (tid >= SEQ) return;
    const int q = tid;
    float qr[32];
#pragma unroll
    for (int f = 0; f < 8; ++f) {
        float4 v = *(const float4*)&qw[(size_t)q * 576 + h * 32 + f * 4];
        qr[f * 4 + 0] = v.x; qr[f * 4 + 1] = v.y;
        qr[f * 4 + 2] = v.z; qr[f * 4 + 3] = v.w;
    }
    const float scale = 0.17677669529663687f;  // 1/sqrt(32)
    const float* mrow = mask + (size_t)wn * SEQ * SEQ;   // symmetric: [k][q] ok
    const float* brow = biasT + (size_t)h * SEQ * SEQ;   // [k][q]
    float m = -1e30f, l = 0.0f;
    float ov[32];
#pragma unroll
    for (int d2 = 0; d2 < 32; ++d2) ov[d2] = 0.0f;
    for (int k0 = 0; k0 < SEQ; k0 += 7) {  // 49 chunks of 7, exact
        float sc[7];
#pragma unroll
        for (int j = 0; j < 7; ++j) {
            const float* kr = Ks[k0 + j];
            float a = 0.0f;
#pragma unroll
            for (int d2 = 0; d2 < 32; ++d2) a += qr[d2] * kr[d2];
            sc[j] = a;
        }
#pragma unroll
        for (int j = 0; j < 7; ++j) {
            int k = k0 + j;
            float mk = mrow[(size_t)k * SEQ + q];
            float bi = brow[(size_t)k * SEQ + q];
            sc[j] = (mk != 0.0f) ? -1e9f : (sc[j] * scale + bi);
        }
        float cm = sc[0];
#pragma unroll
        for (int j = 1; j < 7; ++j) cm = fmaxf(cm, sc[j]);
        if (__any(cm > m)) {
            float mn = fmaxf(m, cm);
            float r = __expf(m - mn);
            l *= r;
#pragma unroll
            for (int d2 = 0; d2 < 32; ++d2) ov[d2] *= r;
            m = mn;
        }
#pragma unroll
        for (int j = 0; j < 7; ++j) {
            float p = __expf(sc[j] - m);
            l += p;
            const float* vr = Vs[k0 + j];
#pragma unroll
            for (int d2 = 0; d2 < 32; ++d2) ov[d2] += p * vr[d2];
        }
    }
    float inv = 1.0f / l;
    float* orow = o + ((size_t)wn * SEQ + q) * CCH + h * 32;
#pragma unroll
    for (int f = 0; f < 8; ++f) {
        float4 v;
        v.x = ov[f * 4 + 0] * inv; v.y = ov[f * 4 + 1] * inv;
        v.z = ov[f * 4 + 2] * inv; v.w = ov[f * 4 + 3] * inv;
        *(float4*)&orow[f * 4] = v;
    }
}

extern "C" void kernel_launch(void* const* d_in, const int* in_sizes, int n_in,
                              void* d_out, int out_size, void* d_ws, size_t ws_size,
                              hipStream_t stream) {
    const float* x     = (const float*)d_in[0];
    const float* mask  = (const float*)d_in[1];
    // d_in[2] = clinical (unused by reference)
    const float* ln1_w = (const float*)d_in[3];
    const float* ln1_b = (const float*)d_in[4];
    const float* qkv_w = (const float*)d_in[5];
    const float* qkv_b = (const float*)d_in[6];
    const float* out_w = (const float*)d_in[7];
    const float* out_b = (const float*)d_in[8];
    const float* ln2_w = (const float*)d_in[9];
    const float* ln2_b = (const float*)d_in[10];
    const float* ff1_w = (const float*)d_in[11];
    const float* ff1_b = (const float*)d_in[12];
    const float* ff2_w = (const float*)d_in[13];
    const float* ff2_b = (const float*)d_in[14];
    const float* rpb   = (const float*)d_in[15];
    const float* lnf_w = (const float*)d_in[16];
    const float* lnf_b = (const float*)d_in[17];
    // d_in[18] = rel_index (recomputed arithmetically on device)

    float* xw    = (float*)d_ws;          // TOK*192
    float* hdn   = xw + (size_t)8429568;  // TOK*192 (LN out / attention out)
    float* qkvb  = hdn + (size_t)8429568; // max(TOK*576, TOK*768)
    float* biasT = qkvb + (size_t)33718272; // 6*343*343
    float* out   = (float*)d_out;

    k_shift_part<<<8232, 256, 0, stream>>>(x, xw);
    for (int l = 0; l < 2; ++l) {
        k_biaspre<<<dim3(SEQ, NHEAD), SEQ, 0, stream>>>(rpb + (size_t)l * 2197 * NHEAD, biasT);
        k_ln<<<10976, 256, 0, stream>>>(xw, ln1_w + l * 192, ln1_b + l * 192, hdn, TOK);
        k_gemm<0><<<dim3(9, 343), 256, 0, stream>>>(hdn, qkv_w + (size_t)l * 110592,
                                                    qkv_b + l * 576, qkvb, TOK, 576, 192, 576);
        k_attn<<<dim3(NHEAD, NWIN), 384, 0, stream>>>(qkvb, mask, biasT, hdn);
        k_gemm<1><<<dim3(3, 343), 256, 0, stream>>>(hdn, out_w + (size_t)l * 36864,
                                                    out_b + l * 192, xw, TOK, 192, 192, 192);
        k_ln<<<10976, 256, 0, stream>>>(xw, ln2_w + l * 192, ln2_b + l * 192, hdn, TOK);
        k_gemm<2><<<dim3(12, 343), 256, 0, stream>>>(hdn, ff1_w + (size_t)l * 294912,
                                                     ff1_b + l * 1536, qkvb, TOK, 768, 192, 1536);
        k_gemm<1><<<dim3(3, 343), 256, 0, stream>>>(qkvb, ff2_w + (size_t)l * 147456,
                                                    ff2_b + l * 192, xw, TOK, 192, 768, 192);
    }
    k_ln_out<<<10976, 256, 0, stream>>>(xw, lnf_w, lnf_b, out);
}

// Round 2
// 865.499 us; speedup vs baseline: 3.8214x; 3.8214x over previous
//
#include <hip/hip_runtime.h>
#include <hip/hip_fp16.h>
#include <math.h>

#define SEQ 343
#define CCH 192
#define NWIN 128
#define NHEAD 6
#define TOK (NWIN * SEQ)  // 43904

typedef __bf16 bf16x8 __attribute__((ext_vector_type(8)));
typedef float f32x4 __attribute__((ext_vector_type(4)));
typedef unsigned short ushort8 __attribute__((ext_vector_type(8)));

__device__ __forceinline__ unsigned short f2bf(float f) {
    unsigned u = __float_as_uint(f);
    u += 0x7FFF + ((u >> 16) & 1);
    return (unsigned short)(u >> 16);
}

__device__ __forceinline__ float gelu_tanh(float x) {
    const float k0 = 0.7978845608028654f;
    const float k1 = 0.044715f;
    float t = tanhf(k0 * (x + k1 * x * x * x));
    return 0.5f * x * (1.0f + t);
}

// ---------------- shift (+3 src) + window partition: x(28,56,28,192) -> xw(128,343,192) fp32
__global__ __launch_bounds__(256) void k_shift_part(const float* __restrict__ x,
                                                    float* __restrict__ xw) {
    int idx = blockIdx.x * 256 + threadIdx.x;  // float4 index
    if (idx >= TOK * 48) return;
    int c4 = idx % 48;
    int tok = idx / 48;
    int t = tok % SEQ;
    int wn = tok / SEQ;
    int tw = t % 7, th = (t / 7) % 7, td = t / 49;
    int ww = wn & 3, wh = (wn >> 2) & 7, wd = wn >> 5;
    int sd = (wd * 7 + td + 3) % 28;
    int sh = (wh * 7 + th + 3) % 56;
    int sw = (ww * 7 + tw + 3) % 28;
    const float4* src = (const float4*)(x + (size_t)((sd * 56 + sh) * 28 + sw) * CCH);
    ((float4*)xw)[idx] = src[c4];
}

// ---------------- LayerNorm fp32 -> bf16 (GEMM A operand)
__global__ __launch_bounds__(256) void k_ln_bf(const float* __restrict__ in,
                                               const float* __restrict__ w,
                                               const float* __restrict__ b,
                                               unsigned short* __restrict__ out, int rows) {
    int row = blockIdx.x * 4 + (threadIdx.x >> 6);
    int lane = threadIdx.x & 63;
    if (row >= rows) return;
    const float* p = in + (size_t)row * CCH;
    float v0 = p[lane], v1 = p[lane + 64], v2 = p[lane + 128];
    float s = v0 + v1 + v2;
#pragma unroll
    for (int off = 32; off > 0; off >>= 1) s += __shfl_xor(s, off);
    float mu = s * (1.0f / 192.0f);
    float d0 = v0 - mu, d1 = v1 - mu, d2 = v2 - mu;
    float vv = d0 * d0 + d1 * d1 + d2 * d2;
#pragma unroll
    for (int off = 32; off > 0; off >>= 1) vv += __shfl_xor(vv, off);
    float rs = rsqrtf(vv * (1.0f / 192.0f) + 1e-5f);
    unsigned short* q = out + (size_t)row * CCH;
    q[lane] = f2bf(d0 * rs * w[lane] + b[lane]);
    q[lane + 64] = f2bf(d1 * rs * w[lane + 64] + b[lane + 64]);
    q[lane + 128] = f2bf(d2 * rs * w[lane + 128] + b[lane + 128]);
}

// ---------------- final LN + window reverse + roll(+3) -> d_out (fp32)
__global__ __launch_bounds__(256) void k_ln_out(const float* __restrict__ xw,
                                                const float* __restrict__ w,
                                                const float* __restrict__ b,
                                                float* __restrict__ out) {
    int row = blockIdx.x * 4 + (threadIdx.x >> 6);
    int lane = threadIdx.x & 63;
    if (row >= TOK) return;
    int d = row / 1568;
    int hh = (row / 28) % 56;
    int wv = row % 28;
    int sd = (d + 25) % 28, sh = (hh + 53) % 56, sw = (wv + 25) % 28;
    int wn = (sd / 7) * 32 + (sh / 7) * 4 + (sw / 7);
    int t = (sd % 7) * 49 + (sh % 7) * 7 + (sw % 7);
    const float* p = xw + ((size_t)wn * SEQ + t) * CCH;
    float v0 = p[lane], v1 = p[lane + 64], v2 = p[lane + 128];
    float s = v0 + v1 + v2;
#pragma unroll
    for (int off = 32; off > 0; off >>= 1) s += __shfl_xor(s, off);
    float mu = s * (1.0f / 192.0f);
    float d0 = v0 - mu, d1 = v1 - mu, d2 = v2 - mu;
    float vv = d0 * d0 + d1 * d1 + d2 * d2;
#pragma unroll
    for (int off = 32; off > 0; off >>= 1) vv += __shfl_xor(vv, off);
    float rs = rsqrtf(vv * (1.0f / 192.0f) + 1e-5f);
    float* q = out + (size_t)row * CCH;
    q[lane] = d0 * rs * w[lane] + b[lane];
    q[lane + 64] = d1 * rs * w[lane + 64] + b[lane + 64];
    q[lane + 128] = d2 * rs * w[lane + 128] + b[lane + 128];
}

// ---------------- weight prep: fp32 [K][N] -> bf16 transposed [N][K], both layers
// wt layout per layer: qkvT(576x192) | outT(192x192) | ff1T(1536x192) | ff2T(192x768)
__global__ __launch_bounds__(256) void k_wprep(const float* __restrict__ qkv_w,
                                               const float* __restrict__ out_w,
                                               const float* __restrict__ ff1_w,
                                               const float* __restrict__ ff2_w,
                                               unsigned short* __restrict__ wt) {
    int idx = blockIdx.x * 256 + threadIdx.x;
    if (idx >= 1179648) return;
    int l = idx / 589824;
    int r = idx - l * 589824;
    const float* src;
    int Kd, Nd, off;
    if (r < 110592)      { src = qkv_w + (size_t)l * 110592; Kd = 192; Nd = 576;  off = r; }
    else if (r < 147456) { src = out_w + (size_t)l * 36864;  Kd = 192; Nd = 192;  off = r - 110592; }
    else if (r < 442368) { src = ff1_w + (size_t)l * 294912; Kd = 192; Nd = 1536; off = r - 147456; }
    else                 { src = ff2_w + (size_t)l * 147456; Kd = 768; Nd = 192;  off = r - 442368; }
    int n = off / Kd, k = off - n * Kd;
    wt[idx] = f2bf(src[(size_t)k * Nd + n]);
}

// ---------------- combined mask+bias table: cb[class][h][kp][q] = f16x2 for k=2kp,2kp+1
// 8 mask classes: (wd==3)*4 + (wh==7)*2 + (ww==3)
__global__ void k_cbgen(const float* __restrict__ mask, const float* __restrict__ rpb,
                        unsigned* __restrict__ cb) {
    int q = threadIdx.x;
    if (q >= SEQ) return;
    int kp = blockIdx.x;   // 0..171
    int h = blockIdx.y;    // 0..5
    int cl = blockIdx.z;   // 0..7
    int wn = ((cl & 4) ? 96 : 0) + ((cl & 2) ? 28 : 0) + ((cl & 1) ? 3 : 0);
    int qd = q / 49, qh = (q / 7) % 7, qw = q % 7;
    unsigned short v[2];
#pragma unroll
    for (int t = 0; t < 2; ++t) {
        int k = 2 * kp + t;
        float val;
        if (k > 342) {
            val = -60000.0f;
        } else {
            float mk = mask[((size_t)wn * SEQ + k) * SEQ + q];  // symmetric in !=0
            if (mk != 0.0f) {
                val = -60000.0f;
            } else {
                int kd = k / 49, kh = (k / 7) % 7, kw = k % 7;
                int rel = (qd - kd + 6) * 169 + (qh - kh + 6) * 13 + (qw - kw + 6);
                val = rpb[(size_t)rel * NHEAD + h];
            }
        }
        v[t] = __half_as_ushort(__float2half_rn(val));
    }
    cb[(((size_t)cl * NHEAD + h) * 172 + kp) * SEQ + q] = (unsigned)v[0] | ((unsigned)v[1] << 16);
}

// ---------------- bf16 MFMA GEMM: C[M x N] = A[M x K] @ WtT, Wt stored [N][K] bf16.
// 128x64 tile, BK=64, 4 waves each 64x32 (4x2 frags of 16x16), mfma_f32_16x16x32_bf16.
// MODE 0: outF = acc + bias (fp32)
// MODE 1: outF += acc + bias (residual, fp32)
// MODE 2: GLU: Wt has 2N rows; outB = bf16( (accU+biasU) * gelu(accG+biasG) )
template <int MODE>
__global__ __launch_bounds__(256) void k_gemm_mfma(const unsigned short* __restrict__ A,
                                                   const unsigned short* __restrict__ Wt,
                                                   const float* __restrict__ bias,
                                                   float* __restrict__ outF,
                                                   unsigned short* __restrict__ outB,
                                                   int N, int K) {
    __shared__ unsigned short As[128][72];
    __shared__ unsigned short Bs[64][72];
    __shared__ unsigned short Bs2[(MODE == 2) ? 64 : 1][72];
    const int tid = threadIdx.x;
    const int n0 = blockIdx.x * 64;
    const size_t m0 = (size_t)blockIdx.y * 128;
    const int lane = tid & 63, wid = tid >> 6;
    const int wr = wid >> 1, wc = wid & 1;
    f32x4 acc[4][2];
    f32x4 acc2[4][2];
#pragma unroll
    for (int m = 0; m < 4; ++m)
#pragma unroll
        for (int n = 0; n < 2; ++n) {
            acc[m][n] = (f32x4){0.f, 0.f, 0.f, 0.f};
            acc2[m][n] = (f32x4){0.f, 0.f, 0.f, 0.f};
        }
    const int arow = wr * 64 + (lane & 15);
    const int bcol = wc * 32 + (lane & 15);
    const int kg = (lane >> 4) * 8;
    for (int kb = 0; kb < K; kb += 64) {
#pragma unroll
        for (int i = 0; i < 4; ++i) {
            int idx = tid + i * 256;
            int r = idx >> 3, ck = (idx & 7) << 3;
            *(ushort8*)&As[r][ck] = *(const ushort8*)&A[(m0 + r) * (size_t)K + kb + ck];
        }
#pragma unroll
        for (int i = 0; i < 2; ++i) {
            int idx = tid + i * 256;
            int r = idx >> 3, ck = (idx & 7) << 3;
            *(ushort8*)&Bs[r][ck] = *(const ushort8*)&Wt[(size_t)(n0 + r) * K + kb + ck];
            if (MODE == 2)
                *(ushort8*)&Bs2[r][ck] = *(const ushort8*)&Wt[(size_t)(N + n0 + r) * K + kb + ck];
        }
        __syncthreads();
#pragma unroll
        for (int kk = 0; kk < 64; kk += 32) {
            bf16x8 a[4], b[2];
#pragma unroll
            for (int m = 0; m < 4; ++m) a[m] = *(const bf16x8*)&As[arow + m * 16][kk + kg];
#pragma unroll
            for (int n = 0; n < 2; ++n) b[n] = *(const bf16x8*)&Bs[bcol + n * 16][kk + kg];
#pragma unroll
            for (int m = 0; m < 4; ++m)
#pragma unroll
                for (int n = 0; n < 2; ++n)
                    acc[m][n] = __builtin_amdgcn_mfma_f32_16x16x32_bf16(a[m], b[n], acc[m][n], 0, 0, 0);
            if (MODE == 2) {
                bf16x8 b2[2];
#pragma unroll
                for (int n = 0; n < 2; ++n) b2[n] = *(const bf16x8*)&Bs2[bcol + n * 16][kk + kg];
#pragma unroll
                for (int m = 0; m < 4; ++m)
#pragma unroll
                    for (int n = 0; n < 2; ++n)
                        acc2[m][n] = __builtin_amdgcn_mfma_f32_16x16x32_bf16(a[m], b2[n], acc2[m][n], 0, 0, 0);
            }
        }
        __syncthreads();
    }
    const int col0 = n0 + wc * 32 + (lane & 15);
    const int row0 = (int)m0 + wr * 64 + ((lane >> 4) << 2);
#pragma unroll
    for (int n = 0; n < 2; ++n) {
        int gc = col0 + n * 16;
        float bb = bias[gc];
        float bg = (MODE == 2) ? bias[N + gc] : 0.f;
#pragma unroll
        for (int m = 0; m < 4; ++m) {
            int gr = row0 + m * 16;
#pragma unroll
            for (int j = 0; j < 4; ++j) {
                size_t o = (size_t)(gr + j) * N + gc;
                if (MODE == 0) {
                    outF[o] = acc[m][n][j] + bb;
                } else if (MODE == 1) {
                    outF[o] += acc[m][n][j] + bb;
                } else {
                    float u = acc[m][n][j] + bb;
                    float g = acc2[m][n][j] + bg;
                    outB[o] = f2bf(u * gelu_tanh(g));
                }
            }
        }
    }
}

// ---------------- attention: block per (head, window); lane = q-row; K/V f16x2 in LDS.
__global__ __launch_bounds__(384) void k_attn2(const float* __restrict__ qkv,
                                               const unsigned* __restrict__ cb,
                                               unsigned short* __restrict__ o) {
    __shared__ __half2 Ks[344][16];
    __shared__ __half2 Vs[344][16];
    const int h = blockIdx.x;
    const int wn = blockIdx.y;
    const int tid = threadIdx.x;
    const float* qw = qkv + (size_t)wn * SEQ * 576;
    const __half2 z2 = __float2half2_rn(0.f);
    for (int j = tid; j < 344 * 8; j += 384) {
        int s = j >> 3, f = j & 7;
        if (s < SEQ) {
            float4 kv = *(const float4*)&qw[(size_t)s * 576 + 192 + h * 32 + f * 4];
            float4 vv = *(const float4*)&qw[(size_t)s * 576 + 384 + h * 32 + f * 4];
            Ks[s][f * 2] = __floats2half2_rn(kv.x, kv.y);
            Ks[s][f * 2 + 1] = __floats2half2_rn(kv.z, kv.w);
            Vs[s][f * 2] = __floats2half2_rn(vv.x, vv.y);
            Vs[s][f * 2 + 1] = __floats2half2_rn(vv.z, vv.w);
        } else {
            Ks[s][f * 2] = z2; Ks[s][f * 2 + 1] = z2;
            Vs[s][f * 2] = z2; Vs[s][f * 2 + 1] = z2;
        }
    }
    __syncthreads();
    if (tid >= SEQ) return;
    const int q = tid;
    const float sc = 0.17677669529663687f;  // 1/sqrt(32)
    __half2 qr[16];
#pragma unroll
    for (int f = 0; f < 8; ++f) {
        float4 v = *(const float4*)&qw[(size_t)q * 576 + h * 32 + f * 4];
        qr[f * 2] = __floats2half2_rn(v.x * sc, v.y * sc);
        qr[f * 2 + 1] = __floats2half2_rn(v.z * sc, v.w * sc);
    }
    int cls = (((wn >> 5) == 3) ? 4 : 0) | ((((wn >> 2) & 7) == 7) ? 2 : 0) | (((wn & 3) == 3) ? 1 : 0);
    const unsigned* cbb = cb + (((size_t)cls * NHEAD + h) * 172) * SEQ + q;
    float m = -1e30f, l = 0.f;
    __half2 ov[16];
#pragma unroll
    for (int d2 = 0; d2 < 16; ++d2) ov[d2] = z2;
    for (int c = 0; c < 43; ++c) {
        float lg[8];
#pragma unroll
        for (int jp = 0; jp < 4; ++jp) {
            int kp = c * 4 + jp;
            unsigned cbv = cbb[(size_t)kp * SEQ];
            __half2 ch = *(__half2*)&cbv;
#pragma unroll
            for (int t = 0; t < 2; ++t) {
                int k = 2 * kp + t;
                __half2 s2 = z2;
#pragma unroll
                for (int d2 = 0; d2 < 16; ++d2) s2 = __hfma2(qr[d2], Ks[k][d2], s2);
                float cbf = t ? __high2float(ch) : __low2float(ch);
                lg[jp * 2 + t] = __low2float(s2) + __high2float(s2) + cbf;
            }
        }
        float cm = lg[0];
#pragma unroll
        for (int j = 1; j < 8; ++j) cm = fmaxf(cm, lg[j]);
        if (__any(cm > m)) {
            float mn = fmaxf(m, cm);
            float r = __expf(m - mn);
            l *= r;
            __half2 r2 = __float2half2_rn(r);
#pragma unroll
            for (int d2 = 0; d2 < 16; ++d2) ov[d2] = __hmul2(ov[d2], r2);
            m = mn;
        }
#pragma unroll
        for (int j = 0; j < 8; ++j) {
            float p = __expf(lg[j] - m);
            l += p;
            __half2 p2 = __float2half2_rn(p);
            int k = c * 8 + j;
#pragma unroll
            for (int d2 = 0; d2 < 16; ++d2) ov[d2] = __hfma2(p2, Vs[k][d2], ov[d2]);
        }
    }
    float inv = 1.0f / l;
    unsigned short* orow = o + ((size_t)wn * SEQ + q) * CCH + h * 32;
#pragma unroll
    for (int d2 = 0; d2 < 16; ++d2) {
        float a = __low2float(ov[d2]) * inv;
        float b = __high2float(ov[d2]) * inv;
        ushort2 pk = {f2bf(a), f2bf(b)};
        *(ushort2*)&orow[d2 * 2] = pk;
    }
}

extern "C" void kernel_launch(void* const* d_in, const int* in_sizes, int n_in,
                              void* d_out, int out_size, void* d_ws, size_t ws_size,
                              hipStream_t stream) {
    const float* x     = (const float*)d_in[0];
    const float* mask  = (const float*)d_in[1];
    const float* ln1_w = (const float*)d_in[3];
    const float* ln1_b = (const float*)d_in[4];
    const float* qkv_w = (const float*)d_in[5];
    const float* qkv_b = (const float*)d_in[6];
    const float* out_w = (const float*)d_in[7];
    const float* out_b = (const float*)d_in[8];
    const float* ln2_w = (const float*)d_in[9];
    const float* ln2_b = (const float*)d_in[10];
    const float* ff1_w = (const float*)d_in[11];
    const float* ff1_b = (const float*)d_in[12];
    const float* ff2_w = (const float*)d_in[13];
    const float* ff2_b = (const float*)d_in[14];
    const float* rpb   = (const float*)d_in[15];
    const float* lnf_w = (const float*)d_in[16];
    const float* lnf_b = (const float*)d_in[17];

    // workspace layout (bytes, all 16B aligned)
    float* xw = (float*)d_ws;                                    // 33,718,272
    unsigned short* hdnb = (unsigned short*)(xw + 8429568);      // 16,859,136 (bf16 [TOK][192])
    float* qkvb = (float*)((char*)hdnb + 16859136);              // 101,154,816 (fp32 [TOK][576])
    unsigned short* glub = (unsigned short*)qkvb;                // bf16 [TOK][768] overlaps qkvb
    unsigned short* wt = (unsigned short*)((char*)qkvb + 101154816);  // 2,359,296
    unsigned* cb = (unsigned*)((char*)wt + 2359296);             // 11,326,848
    float* out = (float*)d_out;

    k_shift_part<<<8232, 256, 0, stream>>>(x, xw);
    k_wprep<<<4608, 256, 0, stream>>>(qkv_w, out_w, ff1_w, ff2_w, wt);
    for (int l = 0; l < 2; ++l) {
        unsigned short* wbase = wt + (size_t)l * 589824;
        k_cbgen<<<dim3(172, NHEAD, 8), SEQ, 0, stream>>>(mask, rpb + (size_t)l * 2197 * NHEAD, cb);
        k_ln_bf<<<10976, 256, 0, stream>>>(xw, ln1_w + l * 192, ln1_b + l * 192, hdnb, TOK);
        k_gemm_mfma<0><<<dim3(9, 343), 256, 0, stream>>>(hdnb, wbase, qkv_b + l * 576,
                                                         qkvb, nullptr, 576, 192);
        k_attn2<<<dim3(NHEAD, NWIN), 384, 0, stream>>>(qkvb, cb, hdnb);
        k_gemm_mfma<1><<<dim3(3, 343), 256, 0, stream>>>(hdnb, wbase + 110592, out_b + l * 192,
                                                         xw, nullptr, 192, 192);
        k_ln_bf<<<10976, 256, 0, stream>>>(xw, ln2_w + l * 192, ln2_b + l * 192, hdnb, TOK);
        k_gemm_mfma<2><<<dim3(12, 343), 256, 0, stream>>>(hdnb, wbase + 147456, ff1_b + l * 1536,
                                                          nullptr, glub, 768, 192);
        k_gemm_mfma<1><<<dim3(3, 343), 256, 0, stream>>>(glub, wbase + 442368, ff2_b + l * 192,
                                                         xw, nullptr, 192, 768);
    }
    k_ln_out<<<10976, 256, 0, stream>>>(xw, lnf_w, lnf_b, out);
}

// Round 3
// 600.726 us; speedup vs baseline: 5.5057x; 1.4408x over previous
//
#include <hip/hip_runtime.h>
#include <hip/hip_fp16.h>
#include <math.h>

#define SEQ 343
#define CCH 192
#define NWIN 128
#define NHEAD 6
#define TOK (NWIN * SEQ)  // 43904

typedef __bf16 bf16x8 __attribute__((ext_vector_type(8)));
typedef float f32x4 __attribute__((ext_vector_type(4)));
typedef unsigned short ushort8 __attribute__((ext_vector_type(8)));
typedef _Float16 half8 __attribute__((ext_vector_type(8)));
typedef _Float16 half4 __attribute__((ext_vector_type(4)));

__device__ __forceinline__ unsigned short f2bf(float f) {
    unsigned u = __float_as_uint(f);
    u += 0x7FFF + ((u >> 16) & 1);
    return (unsigned short)(u >> 16);
}

__device__ __forceinline__ float gelu_tanh(float x) {
    const float k0 = 0.7978845608028654f;
    const float k1 = 0.044715f;
    float t = tanhf(k0 * (x + k1 * x * x * x));
    return 0.5f * x * (1.0f + t);
}

// ---------------- shift (+3 src) + window partition: x(28,56,28,192) -> xw(128,343,192) fp32
__global__ __launch_bounds__(256) void k_shift_part(const float* __restrict__ x,
                                                    float* __restrict__ xw) {
    int idx = blockIdx.x * 256 + threadIdx.x;  // float4 index
    if (idx >= TOK * 48) return;
    int c4 = idx % 48;
    int tok = idx / 48;
    int t = tok % SEQ;
    int wn = tok / SEQ;
    int tw = t % 7, th = (t / 7) % 7, td = t / 49;
    int ww = wn & 3, wh = (wn >> 2) & 7, wd = wn >> 5;
    int sd = (wd * 7 + td + 3) % 28;
    int sh = (wh * 7 + th + 3) % 56;
    int sw = (ww * 7 + tw + 3) % 28;
    const float4* src = (const float4*)(x + (size_t)((sd * 56 + sh) * 28 + sw) * CCH);
    ((float4*)xw)[idx] = src[c4];
}

// ---------------- LayerNorm fp32 -> bf16 (GEMM A operand)
__global__ __launch_bounds__(256) void k_ln_bf(const float* __restrict__ in,
                                               const float* __restrict__ w,
                                               const float* __restrict__ b,
                                               unsigned short* __restrict__ out, int rows) {
    int row = blockIdx.x * 4 + (threadIdx.x >> 6);
    int lane = threadIdx.x & 63;
    if (row >= rows) return;
    const float* p = in + (size_t)row * CCH;
    float v0 = p[lane], v1 = p[lane + 64], v2 = p[lane + 128];
    float s = v0 + v1 + v2;
#pragma unroll
    for (int off = 32; off > 0; off >>= 1) s += __shfl_xor(s, off);
    float mu = s * (1.0f / 192.0f);
    float d0 = v0 - mu, d1 = v1 - mu, d2 = v2 - mu;
    float vv = d0 * d0 + d1 * d1 + d2 * d2;
#pragma unroll
    for (int off = 32; off > 0; off >>= 1) vv += __shfl_xor(vv, off);
    float rs = rsqrtf(vv * (1.0f / 192.0f) + 1e-5f);
    unsigned short* q = out + (size_t)row * CCH;
    q[lane] = f2bf(d0 * rs * w[lane] + b[lane]);
    q[lane + 64] = f2bf(d1 * rs * w[lane + 64] + b[lane + 64]);
    q[lane + 128] = f2bf(d2 * rs * w[lane + 128] + b[lane + 128]);
}

// ---------------- final LN + window reverse + roll(+3) -> d_out (fp32)
__global__ __launch_bounds__(256) void k_ln_out(const float* __restrict__ xw,
                                                const float* __restrict__ w,
                                                const float* __restrict__ b,
                                                float* __restrict__ out) {
    int row = blockIdx.x * 4 + (threadIdx.x >> 6);
    int lane = threadIdx.x & 63;
    if (row >= TOK) return;
    int d = row / 1568;
    int hh = (row / 28) % 56;
    int wv = row % 28;
    int sd = (d + 25) % 28, sh = (hh + 53) % 56, sw = (wv + 25) % 28;
    int wn = (sd / 7) * 32 + (sh / 7) * 4 + (sw / 7);
    int t = (sd % 7) * 49 + (sh % 7) * 7 + (sw % 7);
    const float* p = xw + ((size_t)wn * SEQ + t) * CCH;
    float v0 = p[lane], v1 = p[lane + 64], v2 = p[lane + 128];
    float s = v0 + v1 + v2;
#pragma unroll
    for (int off = 32; off > 0; off >>= 1) s += __shfl_xor(s, off);
    float mu = s * (1.0f / 192.0f);
    float d0 = v0 - mu, d1 = v1 - mu, d2 = v2 - mu;
    float vv = d0 * d0 + d1 * d1 + d2 * d2;
#pragma unroll
    for (int off = 32; off > 0; off >>= 1) vv += __shfl_xor(vv, off);
    float rs = rsqrtf(vv * (1.0f / 192.0f) + 1e-5f);
    float* q = out + (size_t)row * CCH;
    q[lane] = d0 * rs * w[lane] + b[lane];
    q[lane + 64] = d1 * rs * w[lane + 64] + b[lane + 64];
    q[lane + 128] = d2 * rs * w[lane + 128] + b[lane + 128];
}

// ---------------- weight prep: fp32 [K][N] -> bf16 transposed [N][K], both layers
__global__ __launch_bounds__(256) void k_wprep(const float* __restrict__ qkv_w,
                                               const float* __restrict__ out_w,
                                               const float* __restrict__ ff1_w,
                                               const float* __restrict__ ff2_w,
                                               unsigned short* __restrict__ wt) {
    int idx = blockIdx.x * 256 + threadIdx.x;
    if (idx >= 1179648) return;
    int l = idx / 589824;
    int r = idx - l * 589824;
    const float* src;
    int Kd, Nd, off;
    if (r < 110592)      { src = qkv_w + (size_t)l * 110592; Kd = 192; Nd = 576;  off = r; }
    else if (r < 147456) { src = out_w + (size_t)l * 36864;  Kd = 192; Nd = 192;  off = r - 110592; }
    else if (r < 442368) { src = ff1_w + (size_t)l * 294912; Kd = 192; Nd = 1536; off = r - 147456; }
    else                 { src = ff2_w + (size_t)l * 147456; Kd = 768; Nd = 192;  off = r - 442368; }
    int n = off / Kd, k = off - n * Kd;
    wt[idx] = f2bf(src[(size_t)k * Nd + n]);
}

// ---------------- combined mask+bias (log2 domain): cb[cl][h][kp][q], f16 pair for k=2kp,2kp+1
__global__ void k_cbgen2(const float* __restrict__ mask, const float* __restrict__ rpb,
                         unsigned* __restrict__ cb) {
    int q = threadIdx.x;   // 0..351
    int kp = blockIdx.x;   // 0..175
    int h = blockIdx.y;    // 0..5
    int cl = blockIdx.z;   // 0..7
    int wn = ((cl & 4) ? 96 : 0) + ((cl & 2) ? 28 : 0) + ((cl & 1) ? 3 : 0);
    const float LOG2E = 1.4426950408889634f;
    int qd = q / 49, qh = (q / 7) % 7, qw = q % 7;
    unsigned short v[2];
#pragma unroll
    for (int t = 0; t < 2; ++t) {
        int k = 2 * kp + t;
        float val = -14000.0f;
        if (k < SEQ && q < SEQ) {
            float mk = mask[((size_t)wn * SEQ + k) * SEQ + q];  // mask symmetric in !=0
            if (mk == 0.0f) {
                int kd = k / 49, kh = (k / 7) % 7, kw = k % 7;
                int rel = (qd - kd + 6) * 169 + (qh - kh + 6) * 13 + (qw - kw + 6);
                val = rpb[(size_t)rel * NHEAD + h] * LOG2E;
            }
        }
        v[t] = __half_as_ushort(__float2half_rn(val));
    }
    cb[((size_t)(cl * NHEAD + h) * 176 + kp) * 352 + q] = (unsigned)v[0] | ((unsigned)v[1] << 16);
}

// ---------------- bf16 MFMA GEMM. Wt stored [N][K] bf16. 128x64 tile, BK=64, 4 waves.
// MODE 1: outF += acc + bias (residual, fp32)
// MODE 2: GLU: Wt has 2N rows; outB = bf16( (accU+biasU) * gelu(accG+biasG) )
// MODE 3: qkv prep: N=576. cols<192: Q*scale*log2e -> outH f16 [row][384]
//                   cols 192..383: K -> outH. cols>=384: V -> outV [wn][h][d][344] f16 transposed
template <int MODE>
__global__ __launch_bounds__(256) void k_gemm_mfma(const unsigned short* __restrict__ A,
                                                   const unsigned short* __restrict__ Wt,
                                                   const float* __restrict__ bias,
                                                   float* __restrict__ outF,
                                                   unsigned short* __restrict__ outB,
                                                   _Float16* __restrict__ outH,
                                                   _Float16* __restrict__ outV,
                                                   int N, int K) {
    __shared__ unsigned short As[128][72];
    __shared__ unsigned short Bs[64][72];
    __shared__ unsigned short Bs2[(MODE == 2) ? 64 : 1][72];
    const int tid = threadIdx.x;
    const int n0 = blockIdx.x * 64;
    const size_t m0 = (size_t)blockIdx.y * 128;
    const int lane = tid & 63, wid = tid >> 6;
    const int wr = wid >> 1, wc = wid & 1;
    f32x4 acc[4][2];
    f32x4 acc2[4][2];
#pragma unroll
    for (int m = 0; m < 4; ++m)
#pragma unroll
        for (int n = 0; n < 2; ++n) {
            acc[m][n] = (f32x4){0.f, 0.f, 0.f, 0.f};
            acc2[m][n] = (f32x4){0.f, 0.f, 0.f, 0.f};
        }
    const int arow = wr * 64 + (lane & 15);
    const int bcol = wc * 32 + (lane & 15);
    const int kg = (lane >> 4) * 8;
    for (int kb = 0; kb < K; kb += 64) {
#pragma unroll
        for (int i = 0; i < 4; ++i) {
            int idx = tid + i * 256;
            int r = idx >> 3, ck = (idx & 7) << 3;
            *(ushort8*)&As[r][ck] = *(const ushort8*)&A[(m0 + r) * (size_t)K + kb + ck];
        }
#pragma unroll
        for (int i = 0; i < 2; ++i) {
            int idx = tid + i * 256;
            int r = idx >> 3, ck = (idx & 7) << 3;
            *(ushort8*)&Bs[r][ck] = *(const ushort8*)&Wt[(size_t)(n0 + r) * K + kb + ck];
            if (MODE == 2)
                *(ushort8*)&Bs2[r][ck] = *(const ushort8*)&Wt[(size_t)(N + n0 + r) * K + kb + ck];
        }
        __syncthreads();
#pragma unroll
        for (int kk = 0; kk < 64; kk += 32) {
            bf16x8 a[4], b[2];
#pragma unroll
            for (int m = 0; m < 4; ++m) a[m] = *(const bf16x8*)&As[arow + m * 16][kk + kg];
#pragma unroll
            for (int n = 0; n < 2; ++n) b[n] = *(const bf16x8*)&Bs[bcol + n * 16][kk + kg];
#pragma unroll
            for (int m = 0; m < 4; ++m)
#pragma unroll
                for (int n = 0; n < 2; ++n)
                    acc[m][n] = __builtin_amdgcn_mfma_f32_16x16x32_bf16(a[m], b[n], acc[m][n], 0, 0, 0);
            if (MODE == 2) {
                bf16x8 b2[2];
#pragma unroll
                for (int n = 0; n < 2; ++n) b2[n] = *(const bf16x8*)&Bs2[bcol + n * 16][kk + kg];
#pragma unroll
                for (int m = 0; m < 4; ++m)
#pragma unroll
                    for (int n = 0; n < 2; ++n)
                        acc2[m][n] = __builtin_amdgcn_mfma_f32_16x16x32_bf16(a[m], b2[n], acc2[m][n], 0, 0, 0);
            }
        }
        __syncthreads();
    }
    const float S2LOG = 0.17677669529663687f * 1.4426950408889634f;  // scale*log2e
    const int col0 = n0 + wc * 32 + (lane & 15);
    const int row0 = (int)m0 + wr * 64 + ((lane >> 4) << 2);
#pragma unroll
    for (int n = 0; n < 2; ++n) {
        int gc = col0 + n * 16;
        float bb = bias[gc];
        float bg = (MODE == 2) ? bias[N + gc] : 0.f;
#pragma unroll
        for (int m = 0; m < 4; ++m) {
            int gr = row0 + m * 16;
#pragma unroll
            for (int j = 0; j < 4; ++j) {
                float v = acc[m][n][j] + bb;
                size_t o = (size_t)(gr + j) * N + gc;
                if (MODE == 1) {
                    outF[o] += v;
                } else if (MODE == 2) {
                    float g = acc2[m][n][j] + bg;
                    outB[o] = f2bf(v * gelu_tanh(g));
                } else {  // MODE 3
                    int rr = gr + j;
                    if (gc < 384) {
                        outH[(size_t)rr * 384 + gc] = (_Float16)(gc < 192 ? v * S2LOG : v);
                    } else {
                        int d = gc - 384;
                        int hh = d >> 5, dd = d & 31;
                        int wn_ = rr / 343, qq = rr - wn_ * 343;
                        outV[(((size_t)wn_ * NHEAD + hh) * 32 + dd) * 344 + qq] = (_Float16)v;
                    }
                }
            }
        }
    }
}

// ---------------- MFMA attention: block per (head, window), 4 waves, f16 operands.
// S^T = mfma(K, Q^T) so softmax row is lane-local over k; PV via per-wave LDS P buffer.
__global__ __launch_bounds__(256) void k_attn3(const _Float16* __restrict__ qk,  // [TOK][384]
                                               const _Float16* __restrict__ vt,  // [128][6][32][344]
                                               const unsigned* __restrict__ cb,
                                               unsigned short* __restrict__ o) {
    __shared__ _Float16 Ks[352][40];       // 28160 B, A-frag reads conflict-free (pad 40)
    __shared__ _Float16 Vt[32][360];       // 23040 B (pad 360)
    __shared__ _Float16 Pb[4][48][16][4];  // 24576 B, per-wave P buffer [k/4][q][4]
    const int h = blockIdx.x;
    const int wn = blockIdx.y;
    const int tid = threadIdx.x;
    // stage K
    const _Float16* kbase = qk + (size_t)wn * SEQ * 384 + 192 + h * 32;
    for (int j = tid; j < 352 * 4; j += 256) {
        int s = j >> 2, c = (j & 3) * 8;
        half8 v = {};
        if (s < SEQ) v = *(const half8*)&kbase[(size_t)s * 384 + c];
        *(half8*)&Ks[s][c] = v;
    }
    // stage V^T (zero k>=343)
    const _Float16* vbase = vt + ((size_t)wn * NHEAD + h) * 32 * 344;
    for (int j = tid; j < 32 * 44; j += 256) {
        int d = j / 44, c = (j % 44) * 8;
        half8 v = {};
        if (c + 7 <= 342) {
            v = *(const half8*)&vbase[(size_t)d * 344 + c];
        } else if (c <= 342) {
#pragma unroll
            for (int i = 0; i < 8; ++i) v[i] = (c + i <= 342) ? vbase[(size_t)d * 344 + c + i] : (_Float16)0.f;
        }
        *(half8*)&Vt[d][c] = v;
    }
    __syncthreads();
    const int wid = tid >> 6, lane = tid & 63;
    const int qloc = lane & 15, g = lane >> 4;
    int cls = (((wn >> 5) == 3) ? 4 : 0) | ((((wn >> 2) & 7) == 7) ? 2 : 0) | (((wn & 3) == 3) ? 1 : 0);
    const unsigned* cbb = cb + (size_t)(cls * NHEAD + h) * 176 * 352;
    for (int qt = wid; qt < 22; qt += 4) {
        const int q0 = qt * 16;
        const int qrow = q0 + qloc;
        half8 qf = {};
        if (qrow < SEQ) qf = *(const half8*)&qk[((size_t)wn * SEQ + qrow) * 384 + h * 32 + g * 8];
        f32x4 st[22];
#pragma unroll
        for (int kt = 0; kt < 22; ++kt) {
            half8 kf = *(const half8*)&Ks[kt * 16 + qloc][g * 8];
            st[kt] = __builtin_amdgcn_mfma_f32_16x16x32_f16(kf, qf, (f32x4){0.f, 0.f, 0.f, 0.f}, 0, 0, 0);
        }
        // bias (log2 domain) + row max
        float m = -1e30f;
#pragma unroll
        for (int kt = 0; kt < 22; ++kt) {
            const unsigned* cp = cbb + (size_t)(kt * 8 + g * 2) * 352 + q0 + qloc;
            unsigned b0 = cp[0];
            unsigned b1 = cp[352];
            __half2 h0 = *(__half2*)&b0, h1 = *(__half2*)&b1;
            st[kt][0] += __low2float(h0);
            st[kt][1] += __high2float(h0);
            st[kt][2] += __low2float(h1);
            st[kt][3] += __high2float(h1);
            m = fmaxf(m, fmaxf(fmaxf(st[kt][0], st[kt][1]), fmaxf(st[kt][2], st[kt][3])));
        }
        m = fmaxf(m, __shfl_xor(m, 16));
        m = fmaxf(m, __shfl_xor(m, 32));
        float l = 0.f;
        f32x4 acc0 = {0.f, 0.f, 0.f, 0.f}, acc1 = {0.f, 0.f, 0.f, 0.f};
        // ---- pass A: k in [0,192)
        asm volatile("s_waitcnt lgkmcnt(0)" ::: "memory");
#pragma unroll
        for (int kt = 0; kt < 12; ++kt) {
            float p0 = exp2f(st[kt][0] - m), p1 = exp2f(st[kt][1] - m);
            float p2 = exp2f(st[kt][2] - m), p3 = exp2f(st[kt][3] - m);
            l += (p0 + p1) + (p2 + p3);
            half4 pv = {(_Float16)p0, (_Float16)p1, (_Float16)p2, (_Float16)p3};
            *(half4*)&Pb[wid][kt * 4 + g][qloc][0] = pv;
        }
        asm volatile("s_waitcnt lgkmcnt(0)" ::: "memory");
#pragma unroll
        for (int ks = 0; ks < 6; ++ks) {
            half4 pa = *(half4*)&Pb[wid][ks * 8 + g * 2][qloc][0];
            half4 pb = *(half4*)&Pb[wid][ks * 8 + g * 2 + 1][qloc][0];
            half8 pf = {pa[0], pa[1], pa[2], pa[3], pb[0], pb[1], pb[2], pb[3]};
            half8 v0 = *(const half8*)&Vt[qloc][ks * 32 + g * 8];
            half8 v1 = *(const half8*)&Vt[16 + qloc][ks * 32 + g * 8];
            acc0 = __builtin_amdgcn_mfma_f32_16x16x32_f16(v0, pf, acc0, 0, 0, 0);
            acc1 = __builtin_amdgcn_mfma_f32_16x16x32_f16(v1, pf, acc1, 0, 0, 0);
        }
        // ---- pass B: k in [192,352)
        asm volatile("s_waitcnt lgkmcnt(0)" ::: "memory");
#pragma unroll
        for (int kt = 12; kt < 22; ++kt) {
            float p0 = exp2f(st[kt][0] - m), p1 = exp2f(st[kt][1] - m);
            float p2 = exp2f(st[kt][2] - m), p3 = exp2f(st[kt][3] - m);
            l += (p0 + p1) + (p2 + p3);
            half4 pv = {(_Float16)p0, (_Float16)p1, (_Float16)p2, (_Float16)p3};
            *(half4*)&Pb[wid][(kt - 12) * 4 + g][qloc][0] = pv;
        }
        asm volatile("s_waitcnt lgkmcnt(0)" ::: "memory");
#pragma unroll
        for (int ks = 0; ks < 5; ++ks) {
            half4 pa = *(half4*)&Pb[wid][ks * 8 + g * 2][qloc][0];
            half4 pb = *(half4*)&Pb[wid][ks * 8 + g * 2 + 1][qloc][0];
            half8 pf = {pa[0], pa[1], pa[2], pa[3], pb[0], pb[1], pb[2], pb[3]};
            half8 v0 = *(const half8*)&Vt[qloc][192 + ks * 32 + g * 8];
            half8 v1 = *(const half8*)&Vt[16 + qloc][192 + ks * 32 + g * 8];
            acc0 = __builtin_amdgcn_mfma_f32_16x16x32_f16(v0, pf, acc0, 0, 0, 0);
            acc1 = __builtin_amdgcn_mfma_f32_16x16x32_f16(v1, pf, acc1, 0, 0, 0);
        }
        l += __shfl_xor(l, 16);
        l += __shfl_xor(l, 32);
        if (qrow < SEQ) {
            float inv = 1.0f / l;
            unsigned short* orow = o + ((size_t)wn * SEQ + qrow) * CCH + h * 32;
            ushort2 w0 = {f2bf(acc0[0] * inv), f2bf(acc0[1] * inv)};
            ushort2 w1 = {f2bf(acc0[2] * inv), f2bf(acc0[3] * inv)};
            ushort2 w2 = {f2bf(acc1[0] * inv), f2bf(acc1[1] * inv)};
            ushort2 w3 = {f2bf(acc1[2] * inv), f2bf(acc1[3] * inv)};
            *(ushort2*)&orow[g * 4] = w0;
            *(ushort2*)&orow[g * 4 + 2] = w1;
            *(ushort2*)&orow[16 + g * 4] = w2;
            *(ushort2*)&orow[16 + g * 4 + 2] = w3;
        }
    }
}

extern "C" void kernel_launch(void* const* d_in, const int* in_sizes, int n_in,
                              void* d_out, int out_size, void* d_ws, size_t ws_size,
                              hipStream_t stream) {
    const float* x     = (const float*)d_in[0];
    const float* mask  = (const float*)d_in[1];
    const float* ln1_w = (const float*)d_in[3];
    const float* ln1_b = (const float*)d_in[4];
    const float* qkv_w = (const float*)d_in[5];
    const float* qkv_b = (const float*)d_in[6];
    const float* out_w = (const float*)d_in[7];
    const float* out_b = (const float*)d_in[8];
    const float* ln2_w = (const float*)d_in[9];
    const float* ln2_b = (const float*)d_in[10];
    const float* ff1_w = (const float*)d_in[11];
    const float* ff1_b = (const float*)d_in[12];
    const float* ff2_w = (const float*)d_in[13];
    const float* ff2_b = (const float*)d_in[14];
    const float* rpb   = (const float*)d_in[15];
    const float* lnf_w = (const float*)d_in[16];
    const float* lnf_b = (const float*)d_in[17];

    // workspace layout (bytes)
    char* wsp = (char*)d_ws;
    float* xw = (float*)wsp;                          wsp += (size_t)TOK * 192 * 4;   // 33.7 MB
    unsigned short* hdnb = (unsigned short*)wsp;      wsp += (size_t)TOK * 192 * 2;   // 16.9 MB
    _Float16* qkh = (_Float16*)wsp;                   wsp += (size_t)TOK * 384 * 2;   // 33.7 MB
    _Float16* vth = (_Float16*)wsp;                   wsp += (size_t)NWIN * NHEAD * 32 * 344 * 2;  // 16.9 MB
    unsigned short* glub = (unsigned short*)wsp;      wsp += (size_t)TOK * 768 * 2;   // 67.4 MB
    unsigned short* wt = (unsigned short*)wsp;        wsp += (size_t)1179648 * 2;     // 2.36 MB
    unsigned* cb = (unsigned*)wsp;                                                   // 11.9 MB
    float* out = (float*)d_out;

    k_shift_part<<<8232, 256, 0, stream>>>(x, xw);
    k_wprep<<<4608, 256, 0, stream>>>(qkv_w, out_w, ff1_w, ff2_w, wt);
    for (int l = 0; l < 2; ++l) {
        unsigned short* wbase = wt + (size_t)l * 589824;
        k_cbgen2<<<dim3(176, NHEAD, 8), 352, 0, stream>>>(mask, rpb + (size_t)l * 2197 * NHEAD, cb);
        k_ln_bf<<<10976, 256, 0, stream>>>(xw, ln1_w + l * 192, ln1_b + l * 192, hdnb, TOK);
        k_gemm_mfma<3><<<dim3(9, 343), 256, 0, stream>>>(hdnb, wbase, qkv_b + l * 576,
                                                         nullptr, nullptr, qkh, vth, 576, 192);
        k_attn3<<<dim3(NHEAD, NWIN), 256, 0, stream>>>(qkh, vth, cb, hdnb);
        k_gemm_mfma<1><<<dim3(3, 343), 256, 0, stream>>>(hdnb, wbase + 110592, out_b + l * 192,
                                                         xw, nullptr, nullptr, nullptr, 192, 192);
        k_ln_bf<<<10976, 256, 0, stream>>>(xw, ln2_w + l * 192, ln2_b + l * 192, hdnb, TOK);
        k_gemm_mfma<2><<<dim3(12, 343), 256, 0, stream>>>(hdnb, wbase + 147456, ff1_b + l * 1536,
                                                          nullptr, glub, nullptr, nullptr, 768, 192);
        k_gemm_mfma<1><<<dim3(3, 343), 256, 0, stream>>>(glub, wbase + 442368, ff2_b + l * 192,
                                                         xw, nullptr, nullptr, nullptr, 192, 768);
    }
    k_ln_out<<<10976, 256, 0, stream>>>(xw, lnf_w, lnf_b, out);
}

// Round 4
// 575.101 us; speedup vs baseline: 5.7510x; 1.0446x over previous
//
#include <hip/hip_runtime.h>
#include <hip/hip_fp16.h>
#include <math.h>

#define SEQ 343
#define CCH 192
#define NWIN 128
#define NHEAD 6
#define TOK (NWIN * SEQ)  // 43904

typedef __bf16 bf16x8 __attribute__((ext_vector_type(8)));
typedef float f32x4 __attribute__((ext_vector_type(4)));
typedef float f32x16 __attribute__((ext_vector_type(16)));
typedef unsigned short ushort8 __attribute__((ext_vector_type(8)));
typedef _Float16 half8 __attribute__((ext_vector_type(8)));
typedef _Float16 half4 __attribute__((ext_vector_type(4)));

__device__ __forceinline__ unsigned short f2bf(float f) {
    unsigned u = __float_as_uint(f);
    u += 0x7FFF + ((u >> 16) & 1);
    return (unsigned short)(u >> 16);
}

// tanh-approx gelu (matches jax.nn.gelu approximate=True), via fast exp
__device__ __forceinline__ float gelu_tanh(float x) {
    const float k0 = 0.7978845608028654f;
    const float k1 = 0.044715f;
    float y = k0 * (x + k1 * x * x * x);
    float t = 1.0f - 2.0f / (__expf(2.0f * y) + 1.0f);
    return 0.5f * x * (1.0f + t);
}

// async global->LDS, 16B per lane
__device__ __forceinline__ void gld16(void* l, const void* g) {
    __builtin_amdgcn_global_load_lds((const __attribute__((address_space(1))) unsigned int*)g,
                                     (__attribute__((address_space(3))) unsigned int*)l, 16, 0, 0);
}

// ---------------- shift (+3 src) + window partition: x(28,56,28,192) -> xw(128,343,192) fp32
__global__ __launch_bounds__(256) void k_shift_part(const float* __restrict__ x,
                                                    float* __restrict__ xw) {
    int idx = blockIdx.x * 256 + threadIdx.x;  // float4 index
    if (idx >= TOK * 48) return;
    int c4 = idx % 48;
    int tok = idx / 48;
    int t = tok % SEQ;
    int wn = tok / SEQ;
    int tw = t % 7, th = (t / 7) % 7, td = t / 49;
    int ww = wn & 3, wh = (wn >> 2) & 7, wd = wn >> 5;
    int sd = (wd * 7 + td + 3) % 28;
    int sh = (wh * 7 + th + 3) % 56;
    int sw = (ww * 7 + tw + 3) % 28;
    const float4* src = (const float4*)(x + (size_t)((sd * 56 + sh) * 28 + sw) * CCH);
    ((float4*)xw)[idx] = src[c4];
}

// ---------------- LayerNorm fp32 -> bf16 (GEMM A operand)
__global__ __launch_bounds__(256) void k_ln_bf(const float* __restrict__ in,
                                               const float* __restrict__ w,
                                               const float* __restrict__ b,
                                               unsigned short* __restrict__ out, int rows) {
    int row = blockIdx.x * 4 + (threadIdx.x >> 6);
    int lane = threadIdx.x & 63;
    if (row >= rows) return;
    const float* p = in + (size_t)row * CCH;
    float v0 = p[lane], v1 = p[lane + 64], v2 = p[lane + 128];
    float s = v0 + v1 + v2;
#pragma unroll
    for (int off = 32; off > 0; off >>= 1) s += __shfl_xor(s, off);
    float mu = s * (1.0f / 192.0f);
    float d0 = v0 - mu, d1 = v1 - mu, d2 = v2 - mu;
    float vv = d0 * d0 + d1 * d1 + d2 * d2;
#pragma unroll
    for (int off = 32; off > 0; off >>= 1) vv += __shfl_xor(vv, off);
    float rs = rsqrtf(vv * (1.0f / 192.0f) + 1e-5f);
    unsigned short* q = out + (size_t)row * CCH;
    q[lane] = f2bf(d0 * rs * w[lane] + b[lane]);
    q[lane + 64] = f2bf(d1 * rs * w[lane + 64] + b[lane + 64]);
    q[lane + 128] = f2bf(d2 * rs * w[lane + 128] + b[lane + 128]);
}

// ---------------- final LN + window reverse + roll(+3) -> d_out (fp32)
__global__ __launch_bounds__(256) void k_ln_out(const float* __restrict__ xw,
                                                const float* __restrict__ w,
                                                const float* __restrict__ b,
                                                float* __restrict__ out) {
    int row = blockIdx.x * 4 + (threadIdx.x >> 6);
    int lane = threadIdx.x & 63;
    if (row >= TOK) return;
    int d = row / 1568;
    int hh = (row / 28) % 56;
    int wv = row % 28;
    int sd = (d + 25) % 28, sh = (hh + 53) % 56, sw = (wv + 25) % 28;
    int wn = (sd / 7) * 32 + (sh / 7) * 4 + (sw / 7);
    int t = (sd % 7) * 49 + (sh % 7) * 7 + (sw % 7);
    const float* p = xw + ((size_t)wn * SEQ + t) * CCH;
    float v0 = p[lane], v1 = p[lane + 64], v2 = p[lane + 128];
    float s = v0 + v1 + v2;
#pragma unroll
    for (int off = 32; off > 0; off >>= 1) s += __shfl_xor(s, off);
    float mu = s * (1.0f / 192.0f);
    float d0 = v0 - mu, d1 = v1 - mu, d2 = v2 - mu;
    float vv = d0 * d0 + d1 * d1 + d2 * d2;
#pragma unroll
    for (int off = 32; off > 0; off >>= 1) vv += __shfl_xor(vv, off);
    float rs = rsqrtf(vv * (1.0f / 192.0f) + 1e-5f);
    float* q = out + (size_t)row * CCH;
    q[lane] = d0 * rs * w[lane] + b[lane];
    q[lane + 64] = d1 * rs * w[lane + 64] + b[lane + 64];
    q[lane + 128] = d2 * rs * w[lane + 128] + b[lane + 128];
}

// ---------------- weight prep: fp32 [K][N] -> bf16 transposed [N][K], both layers
__global__ __launch_bounds__(256) void k_wprep(const float* __restrict__ qkv_w,
                                               const float* __restrict__ out_w,
                                               const float* __restrict__ ff1_w,
                                               const float* __restrict__ ff2_w,
                                               unsigned short* __restrict__ wt) {
    int idx = blockIdx.x * 256 + threadIdx.x;
    if (idx >= 1179648) return;
    int l = idx / 589824;
    int r = idx - l * 589824;
    const float* src;
    int Kd, Nd, off;
    if (r < 110592)      { src = qkv_w + (size_t)l * 110592; Kd = 192; Nd = 576;  off = r; }
    else if (r < 147456) { src = out_w + (size_t)l * 36864;  Kd = 192; Nd = 192;  off = r - 110592; }
    else if (r < 442368) { src = ff1_w + (size_t)l * 294912; Kd = 192; Nd = 1536; off = r - 147456; }
    else                 { src = ff2_w + (size_t)l * 147456; Kd = 768; Nd = 192;  off = r - 442368; }
    int n = off / Kd, k = off - n * Kd;
    wt[idx] = f2bf(src[(size_t)k * Nd + n]);
}

// ---------------- combined mask+bias (log2 domain): cb[cl][h][kp][q], f16 pair for k=2kp,2kp+1
__global__ void k_cbgen2(const float* __restrict__ mask, const float* __restrict__ rpb,
                         unsigned* __restrict__ cb) {
    int q = threadIdx.x;   // 0..351
    int kp = blockIdx.x;   // 0..175
    int h = blockIdx.y;    // 0..5
    int cl = blockIdx.z;   // 0..7
    int wn = ((cl & 4) ? 96 : 0) + ((cl & 2) ? 28 : 0) + ((cl & 1) ? 3 : 0);
    const float LOG2E = 1.4426950408889634f;
    int qd = q / 49, qh = (q / 7) % 7, qw = q % 7;
    unsigned short v[2];
#pragma unroll
    for (int t = 0; t < 2; ++t) {
        int k = 2 * kp + t;
        float val = -14000.0f;
        if (k < SEQ && q < SEQ) {
            float mk = mask[((size_t)wn * SEQ + k) * SEQ + q];  // mask symmetric in !=0
            if (mk == 0.0f) {
                int kd = k / 49, kh = (k / 7) % 7, kw = k % 7;
                int rel = (qd - kd + 6) * 169 + (qh - kh + 6) * 13 + (qw - kw + 6);
                val = rpb[(size_t)rel * NHEAD + h] * LOG2E;
            }
        }
        v[t] = __half_as_ushort(__float2half_rn(val));
    }
    cb[((size_t)(cl * NHEAD + h) * 176 + kp) * 352 + q] = (unsigned)v[0] | ((unsigned)v[1] << 16);
}

// ---------------- 32x32x16 MFMA GEMM, global_load_lds staging, swizzled LDS (linear dest,
// pre-swizzled global source; read applies same XOR). BM=128, BK=64 (rows = 128B exactly).
// MODE 0 (qkv): BN=192, grid.x in {0,1,2} -> Q(scaled)/K -> outH[row][384]; V -> outV transposed.
// MODE 1: BN=64, outF[row*N+col] += acc + bias  (residual fp32)
// MODE 2 (GLU): BN=64, Wt rows [n0,n0+64)=u, [768+n0,...)=g; outB = bf16(u * gelu(g))
template <int MODE>
__global__ __launch_bounds__(256) void k_gemm32(const unsigned short* __restrict__ A,
                                                const unsigned short* __restrict__ Wt,
                                                const float* __restrict__ bias,
                                                float* __restrict__ outF,
                                                unsigned short* __restrict__ outB,
                                                _Float16* __restrict__ outH,
                                                _Float16* __restrict__ outV,
                                                int N, int K) {
    constexpr int BN = (MODE == 0) ? 192 : 64;
    constexpr int NF = (MODE == 0) ? 3 : 1;          // n-frags (of 32) per wave
    constexpr int WNC = NF * 32;                     // wave n-extent
    constexpr int BROWS = (MODE == 0) ? 192 : ((MODE == 2) ? 128 : 64);
    constexpr int BCH = (BROWS * 128) / 4096;        // B DMA chunks
    __shared__ char AsB[16384];
    __shared__ char BsB[BROWS * 128];
    const int tid = threadIdx.x;
    const int n0 = blockIdx.x * BN;
    const size_t m0 = (size_t)blockIdx.y * 128;
    const int lane = tid & 63, wid = tid >> 6;
    const int wm = wid >> 1, wn = wid & 1;
    const int ln31 = lane & 31, hi16 = (lane >> 5) * 16;
    const int xorv = (ln31 & 7) << 4;
    const size_t ldb = (size_t)K * 2;  // row pitch (bytes) of both A and Wt

    f32x16 acc[2][NF];
    f32x16 accG[2];
#pragma unroll
    for (int mi = 0; mi < 2; ++mi) {
#pragma unroll
        for (int nj = 0; nj < NF; ++nj) acc[mi][nj] = (f32x16)(0.f);
        accG[mi] = (f32x16)(0.f);
    }

    for (int kb = 0; kb < K; kb += 64) {
        // ---- stage A (16 KB) + B via DMA, global source pre-swizzled
#pragma unroll
        for (int i = 0; i < 4; ++i) {
            int s = i * 4096 + tid * 16;
            int r = s >> 7;
            int cb = (s & 127) ^ ((r & 7) << 4);
            gld16(AsB + s, (const char*)A + (m0 + r) * ldb + (size_t)kb * 2 + cb);
        }
#pragma unroll
        for (int i = 0; i < BCH; ++i) {
            int s = i * 4096 + tid * 16;
            int r = s >> 7;
            int cb = (s & 127) ^ ((r & 7) << 4);
            int grow = n0 + r + ((MODE == 2 && r >= 64) ? 704 : 0);
            gld16(BsB + s, (const char*)Wt + (size_t)grow * ldb + (size_t)kb * 2 + cb);
        }
        __syncthreads();
        // ---- compute 4 k-steps of 16
#pragma unroll
        for (int ks = 0; ks < 4; ++ks) {
            const int ccb = (ks * 32 + hi16) ^ xorv;
            bf16x8 a0 = *(const bf16x8*)(AsB + (wm * 64 + ln31) * 128 + ccb);
            bf16x8 a1 = *(const bf16x8*)(AsB + (wm * 64 + 32 + ln31) * 128 + ccb);
            if (MODE == 2) {
                bf16x8 bu = *(const bf16x8*)(BsB + (wn * 32 + ln31) * 128 + ccb);
                bf16x8 bg = *(const bf16x8*)(BsB + (64 + wn * 32 + ln31) * 128 + ccb);
                acc[0][0] = __builtin_amdgcn_mfma_f32_32x32x16_bf16(a0, bu, acc[0][0], 0, 0, 0);
                acc[1][0] = __builtin_amdgcn_mfma_f32_32x32x16_bf16(a1, bu, acc[1][0], 0, 0, 0);
                accG[0] = __builtin_amdgcn_mfma_f32_32x32x16_bf16(a0, bg, accG[0], 0, 0, 0);
                accG[1] = __builtin_amdgcn_mfma_f32_32x32x16_bf16(a1, bg, accG[1], 0, 0, 0);
            } else {
#pragma unroll
                for (int nj = 0; nj < NF; ++nj) {
                    bf16x8 b = *(const bf16x8*)(BsB + (wn * WNC + nj * 32 + ln31) * 128 + ccb);
                    acc[0][nj] = __builtin_amdgcn_mfma_f32_32x32x16_bf16(a0, b, acc[0][nj], 0, 0, 0);
                    acc[1][nj] = __builtin_amdgcn_mfma_f32_32x32x16_bf16(a1, b, acc[1][nj], 0, 0, 0);
                }
            }
        }
        __syncthreads();
    }

    // ---- epilogue. C/D: col=lane&31, row=(reg&3)+8*(reg>>2)+4*(lane>>5)
    const float S2LOG = 0.17677669529663687f * 1.4426950408889634f;  // scale*log2e
    const int rbase = (int)m0 + wm * 64 + ((lane >> 5) << 2);
    const int cbase = n0 + wn * WNC + ln31;
#pragma unroll
    for (int mi = 0; mi < 2; ++mi) {
#pragma unroll
        for (int nj = 0; nj < NF; ++nj) {
            const int gc = cbase + nj * 32;
            const float bb = bias[gc];
            const float bgv = (MODE == 2) ? bias[768 + gc] : 0.f;
#pragma unroll
            for (int reg = 0; reg < 16; ++reg) {
                const int row = rbase + mi * 32 + (reg & 3) + ((reg >> 2) << 3);
                float v = acc[mi][nj][reg] + bb;
                if (MODE == 1) {
                    outF[(size_t)row * N + gc] += v;
                } else if (MODE == 0) {
                    if (n0 < 384) {
                        outH[(size_t)row * 384 + gc] = (_Float16)(n0 == 0 ? v * S2LOG : v);
                    } else {
                        int d = gc - 384, hh = d >> 5, dd = d & 31;
                        int wnn = row / 343, qq = row - wnn * 343;
                        outV[(((size_t)wnn * NHEAD + hh) * 32 + dd) * 344 + qq] = (_Float16)v;
                    }
                } else {
                    float g = accG[mi][reg] + bgv;
                    outB[(size_t)row * 768 + gc] = f2bf(v * gelu_tanh(g));
                }
            }
        }
    }
}

// ---------------- MFMA attention: block per (head, window), 4 waves, f16 operands.
__global__ __launch_bounds__(256) void k_attn3(const _Float16* __restrict__ qk,  // [TOK][384]
                                               const _Float16* __restrict__ vt,  // [128][6][32][344]
                                               const unsigned* __restrict__ cb,
                                               unsigned short* __restrict__ o) {
    __shared__ _Float16 Ks[352][40];
    __shared__ _Float16 Vt[32][360];
    __shared__ _Float16 Pb[4][48][16][4];
    const int h = blockIdx.x;
    const int wn = blockIdx.y;
    const int tid = threadIdx.x;
    const _Float16* kbase = qk + (size_t)wn * SEQ * 384 + 192 + h * 32;
    for (int j = tid; j < 352 * 4; j += 256) {
        int s = j >> 2, c = (j & 3) * 8;
        half8 v = {};
        if (s < SEQ) v = *(const half8*)&kbase[(size_t)s * 384 + c];
        *(half8*)&Ks[s][c] = v;
    }
    const _Float16* vbase = vt + ((size_t)wn * NHEAD + h) * 32 * 344;
    for (int j = tid; j < 32 * 44; j += 256) {
        int d = j / 44, c = (j % 44) * 8;
        half8 v = {};
        if (c + 7 <= 342) {
            v = *(const half8*)&vbase[(size_t)d * 344 + c];
        } else if (c <= 342) {
#pragma unroll
            for (int i = 0; i < 8; ++i) v[i] = (c + i <= 342) ? vbase[(size_t)d * 344 + c + i] : (_Float16)0.f;
        }
        *(half8*)&Vt[d][c] = v;
    }
    __syncthreads();
    const int wid = tid >> 6, lane = tid & 63;
    const int qloc = lane & 15, g = lane >> 4;
    int cls = (((wn >> 5) == 3) ? 4 : 0) | ((((wn >> 2) & 7) == 7) ? 2 : 0) | (((wn & 3) == 3) ? 1 : 0);
    const unsigned* cbb = cb + (size_t)(cls * NHEAD + h) * 176 * 352;
    for (int qt = wid; qt < 22; qt += 4) {
        const int q0 = qt * 16;
        const int qrow = q0 + qloc;
        half8 qf = {};
        if (qrow < SEQ) qf = *(const half8*)&qk[((size_t)wn * SEQ + qrow) * 384 + h * 32 + g * 8];
        f32x4 st[22];
#pragma unroll
        for (int kt = 0; kt < 22; ++kt) {
            half8 kf = *(const half8*)&Ks[kt * 16 + qloc][g * 8];
            st[kt] = __builtin_amdgcn_mfma_f32_16x16x32_f16(kf, qf, (f32x4){0.f, 0.f, 0.f, 0.f}, 0, 0, 0);
        }
        float m = -1e30f;
#pragma unroll
        for (int kt = 0; kt < 22; ++kt) {
            const unsigned* cp = cbb + (size_t)(kt * 8 + g * 2) * 352 + q0 + qloc;
            unsigned b0 = cp[0];
            unsigned b1 = cp[352];
            __half2 h0 = *(__half2*)&b0, h1 = *(__half2*)&b1;
            st[kt][0] += __low2float(h0);
            st[kt][1] += __high2float(h0);
            st[kt][2] += __low2float(h1);
            st[kt][3] += __high2float(h1);
            m = fmaxf(m, fmaxf(fmaxf(st[kt][0], st[kt][1]), fmaxf(st[kt][2], st[kt][3])));
        }
        m = fmaxf(m, __shfl_xor(m, 16));
        m = fmaxf(m, __shfl_xor(m, 32));
        float l = 0.f;
        f32x4 acc0 = {0.f, 0.f, 0.f, 0.f}, acc1 = {0.f, 0.f, 0.f, 0.f};
        asm volatile("s_waitcnt lgkmcnt(0)" ::: "memory");
#pragma unroll
        for (int kt = 0; kt < 12; ++kt) {
            float p0 = exp2f(st[kt][0] - m), p1 = exp2f(st[kt][1] - m);
            float p2 = exp2f(st[kt][2] - m), p3 = exp2f(st[kt][3] - m);
            l += (p0 + p1) + (p2 + p3);
            half4 pv = {(_Float16)p0, (_Float16)p1, (_Float16)p2, (_Float16)p3};
            *(half4*)&Pb[wid][kt * 4 + g][qloc][0] = pv;
        }
        asm volatile("s_waitcnt lgkmcnt(0)" ::: "memory");
#pragma unroll
        for (int ks = 0; ks < 6; ++ks) {
            half4 pa = *(half4*)&Pb[wid][ks * 8 + g * 2][qloc][0];
            half4 pb = *(half4*)&Pb[wid][ks * 8 + g * 2 + 1][qloc][0];
            half8 pf = {pa[0], pa[1], pa[2], pa[3], pb[0], pb[1], pb[2], pb[3]};
            half8 v0 = *(const half8*)&Vt[qloc][ks * 32 + g * 8];
            half8 v1 = *(const half8*)&Vt[16 + qloc][ks * 32 + g * 8];
            acc0 = __builtin_amdgcn_mfma_f32_16x16x32_f16(v0, pf, acc0, 0, 0, 0);
            acc1 = __builtin_amdgcn_mfma_f32_16x16x32_f16(v1, pf, acc1, 0, 0, 0);
        }
        asm volatile("s_waitcnt lgkmcnt(0)" ::: "memory");
#pragma unroll
        for (int kt = 12; kt < 22; ++kt) {
            float p0 = exp2f(st[kt][0] - m), p1 = exp2f(st[kt][1] - m);
            float p2 = exp2f(st[kt][2] - m), p3 = exp2f(st[kt][3] - m);
            l += (p0 + p1) + (p2 + p3);
            half4 pv = {(_Float16)p0, (_Float16)p1, (_Float16)p2, (_Float16)p3};
            *(half4*)&Pb[wid][(kt - 12) * 4 + g][qloc][0] = pv;
        }
        asm volatile("s_waitcnt lgkmcnt(0)" ::: "memory");
#pragma unroll
        for (int ks = 0; ks < 5; ++ks) {
            half4 pa = *(half4*)&Pb[wid][ks * 8 + g * 2][qloc][0];
            half4 pb = *(half4*)&Pb[wid][ks * 8 + g * 2 + 1][qloc][0];
            half8 pf = {pa[0], pa[1], pa[2], pa[3], pb[0], pb[1], pb[2], pb[3]};
            half8 v0 = *(const half8*)&Vt[qloc][192 + ks * 32 + g * 8];
            half8 v1 = *(const half8*)&Vt[16 + qloc][192 + ks * 32 + g * 8];
            acc0 = __builtin_amdgcn_mfma_f32_16x16x32_f16(v0, pf, acc0, 0, 0, 0);
            acc1 = __builtin_amdgcn_mfma_f32_16x16x32_f16(v1, pf, acc1, 0, 0, 0);
        }
        l += __shfl_xor(l, 16);
        l += __shfl_xor(l, 32);
        if (qrow < SEQ) {
            float inv = 1.0f / l;
            unsigned short* orow = o + ((size_t)wn * SEQ + qrow) * CCH + h * 32;
            ushort2 w0 = {f2bf(acc0[0] * inv), f2bf(acc0[1] * inv)};
            ushort2 w1 = {f2bf(acc0[2] * inv), f2bf(acc0[3] * inv)};
            ushort2 w2 = {f2bf(acc1[0] * inv), f2bf(acc1[1] * inv)};
            ushort2 w3 = {f2bf(acc1[2] * inv), f2bf(acc1[3] * inv)};
            *(ushort2*)&orow[g * 4] = w0;
            *(ushort2*)&orow[g * 4 + 2] = w1;
            *(ushort2*)&orow[16 + g * 4] = w2;
            *(ushort2*)&orow[16 + g * 4 + 2] = w3;
        }
    }
}

extern "C" void kernel_launch(void* const* d_in, const int* in_sizes, int n_in,
                              void* d_out, int out_size, void* d_ws, size_t ws_size,
                              hipStream_t stream) {
    const float* x     = (const float*)d_in[0];
    const float* mask  = (const float*)d_in[1];
    const float* ln1_w = (const float*)d_in[3];
    const float* ln1_b = (const float*)d_in[4];
    const float* qkv_w = (const float*)d_in[5];
    const float* qkv_b = (const float*)d_in[6];
    const float* out_w = (const float*)d_in[7];
    const float* out_b = (const float*)d_in[8];
    const float* ln2_w = (const float*)d_in[9];
    const float* ln2_b = (const float*)d_in[10];
    const float* ff1_w = (const float*)d_in[11];
    const float* ff1_b = (const float*)d_in[12];
    const float* ff2_w = (const float*)d_in[13];
    const float* ff2_b = (const float*)d_in[14];
    const float* rpb   = (const float*)d_in[15];
    const float* lnf_w = (const float*)d_in[16];
    const float* lnf_b = (const float*)d_in[17];

    char* wsp = (char*)d_ws;
    float* xw = (float*)wsp;                          wsp += (size_t)TOK * 192 * 4;
    unsigned short* hdnb = (unsigned short*)wsp;      wsp += (size_t)TOK * 192 * 2;
    _Float16* qkh = (_Float16*)wsp;                   wsp += (size_t)TOK * 384 * 2;
    _Float16* vth = (_Float16*)wsp;                   wsp += (size_t)NWIN * NHEAD * 32 * 344 * 2;
    unsigned short* glub = (unsigned short*)wsp;      wsp += (size_t)TOK * 768 * 2;
    unsigned short* wt = (unsigned short*)wsp;        wsp += (size_t)1179648 * 2;
    unsigned* cb = (unsigned*)wsp;
    float* out = (float*)d_out;

    k_shift_part<<<8232, 256, 0, stream>>>(x, xw);
    k_wprep<<<4608, 256, 0, stream>>>(qkv_w, out_w, ff1_w, ff2_w, wt);
    for (int l = 0; l < 2; ++l) {
        unsigned short* wbase = wt + (size_t)l * 589824;
        k_cbgen2<<<dim3(176, NHEAD, 8), 352, 0, stream>>>(mask, rpb + (size_t)l * 2197 * NHEAD, cb);
        k_ln_bf<<<10976, 256, 0, stream>>>(xw, ln1_w + l * 192, ln1_b + l * 192, hdnb, TOK);
        k_gemm32<0><<<dim3(3, 343), 256, 0, stream>>>(hdnb, wbase, qkv_b + l * 576,
                                                      nullptr, nullptr, qkh, vth, 576, 192);
        k_attn3<<<dim3(NHEAD, NWIN), 256, 0, stream>>>(qkh, vth, cb, hdnb);
        k_gemm32<1><<<dim3(3, 343), 256, 0, stream>>>(hdnb, wbase + 110592, out_b + l * 192,
                                                      xw, nullptr, nullptr, nullptr, 192, 192);
        k_ln_bf<<<10976, 256, 0, stream>>>(xw, ln2_w + l * 192, ln2_b + l * 192, hdnb, TOK);
        k_gemm32<2><<<dim3(12, 343), 256, 0, stream>>>(hdnb, wbase + 147456, ff1_b + l * 1536,
                                                       nullptr, glub, nullptr, nullptr, 768, 192);
        k_gemm32<1><<<dim3(3, 343), 256, 0, stream>>>(glub, wbase + 442368, ff2_b + l * 192,
                                                      xw, nullptr, nullptr, nullptr, 192, 768);
    }
    k_ln_out<<<10976, 256, 0, stream>>>(xw, lnf_w, lnf_b, out);
}